// Round 1
// baseline (1164.426 us; speedup 1.0000x reference)
//
#include <hip/hip_runtime.h>

constexpr int N_NODES = 100000;
constexpr int N_EDGES = 1600000;
constexpr int D_IN   = 512;
constexpr int H_DIM  = 128;
constexpr int D_OUT  = 64;
constexpr float ALPHA = 0.1f;

// ---------------- CSC build ----------------

__global__ void k_init(int* __restrict__ deg, int* __restrict__ cursor, int n) {
    int i = blockIdx.x * blockDim.x + threadIdx.x;
    if (i < n) { deg[i] = 0; cursor[i] = 0; }
}

__global__ void k_count(const int* __restrict__ col, int* __restrict__ deg, int e) {
    int i = blockIdx.x * blockDim.x + threadIdx.x;
    if (i < e) atomicAdd(&deg[col[i]], 1);
}

__global__ void k_dinv(const int* __restrict__ deg, float* __restrict__ dinv, int n) {
    int i = blockIdx.x * blockDim.x + threadIdx.x;
    if (i < n) dinv[i] = rsqrtf((float)(deg[i] + 1));   // +1 self loop; deg>=1 always
}

// single-block exclusive scan of in-degrees -> CSC offsets
__global__ __launch_bounds__(1024) void k_scan(const int* __restrict__ deg,
                                               int* __restrict__ offsets, int n) {
    __shared__ int sums[1024];
    int t = threadIdx.x;
    int chunk = (n + 1023) / 1024;
    int begin = t * chunk;
    int end = begin + chunk; if (end > n) end = n;
    int s = 0;
    for (int i = begin; i < end; ++i) s += deg[i];
    sums[t] = s;
    __syncthreads();
    for (int off = 1; off < 1024; off <<= 1) {
        int v = (t >= off) ? sums[t - off] : 0;
        __syncthreads();
        sums[t] += v;
        __syncthreads();
    }
    int run = (t == 0) ? 0 : sums[t - 1];
    for (int i = begin; i < end; ++i) { offsets[i] = run; run += deg[i]; }
    if (t == 1023) offsets[n] = run;    // == E
}

__global__ void k_fill(const int* __restrict__ row, const int* __restrict__ col,
                       const int* __restrict__ offsets, int* __restrict__ cursor,
                       const float* __restrict__ dinv,
                       int* __restrict__ srcA, float* __restrict__ wgt, int e) {
    int i = blockIdx.x * blockDim.x + threadIdx.x;
    if (i >= e) return;
    int r = row[i], c = col[i];
    int p = offsets[c] + atomicAdd(&cursor[c], 1);
    srcA[p] = r;
    wgt[p]  = dinv[r] * dinv[c];
}

// ---------------- aggregation: one wave per node, float2/lane ----------------
// z = (1-a) * (dinv_i^2 * hcur[i] + sum_in norm * hcur[src]) + a * h0[i]

__global__ __launch_bounds__(256) void k_agg(const float* __restrict__ hcur,
        const float* __restrict__ h0,
        const int* __restrict__ offsets, const int* __restrict__ srcA,
        const float* __restrict__ wgt, const float* __restrict__ dinv,
        float* __restrict__ z, int n) {
    int wid  = (int)((blockIdx.x * (unsigned)blockDim.x + threadIdx.x) >> 6);
    int lane = threadIdx.x & 63;
    if (wid >= n) return;
    float di = dinv[wid];
    const float oma = 1.0f - ALPHA;
    int o0 = offsets[wid], o1 = offsets[wid + 1];
    float2 hc = ((const float2*)(hcur + (size_t)wid * H_DIM))[lane];
    float2 hz = ((const float2*)(h0   + (size_t)wid * H_DIM))[lane];
    float sw = oma * di * di;
    float2 acc;
    acc.x = sw * hc.x + ALPHA * hz.x;
    acc.y = sw * hc.y + ALPHA * hz.y;
    for (int p2 = o0; p2 < o1; ++p2) {
        int s = srcA[p2];
        float wv = oma * wgt[p2];
        float2 hs = ((const float2*)(hcur + (size_t)s * H_DIM))[lane];
        acc.x += wv * hs.x;
        acc.y += wv * hs.y;
    }
    ((float2*)(z + (size_t)wid * H_DIM))[lane] = acc;
}

// ---------------- f32 tiled GEMM: C[M,BN] = act(A[M,K] @ B[K,BN] + bias) ----------------
// B row stride == BN (full matrix width handled by one block column).

template<int BN, bool RELU, bool BIAS>
__global__ __launch_bounds__(256) void k_gemm(const float* __restrict__ A,
        const float* __restrict__ B, const float* __restrict__ bias,
        float* __restrict__ C, int M, int K) {
    constexpr int BM = 64, BK = 32;
    constexpr int TXN = BN / 8;        // threads across cols (8 cols/thread)
    constexpr int TYN = 256 / TXN;     // threads across rows
    constexpr int RPT = BM / TYN;      // rows per thread
    __shared__ float As[BK][BM + 4];   // [k][m], pad keeps 16B alignment
    __shared__ float Bs[BK][BN];
    int tid = threadIdx.x;
    int tx = tid % TXN, ty = tid / TXN;
    int bm = blockIdx.x * BM;
    float acc[RPT][8];
#pragma unroll
    for (int r = 0; r < RPT; ++r)
#pragma unroll
        for (int j = 0; j < 8; ++j) acc[r][j] = 0.f;

    for (int k0 = 0; k0 < K; k0 += BK) {
#pragma unroll
        for (int i = 0; i < (BM * BK) / 256; ++i) {
            int idx = tid + i * 256;
            int m = idx / BK, k = idx % BK;
            int gr = bm + m;
            As[k][m] = (gr < M) ? A[(size_t)gr * K + (k0 + k)] : 0.f;
        }
#pragma unroll
        for (int i = 0; i < (BK * BN) / 256; ++i) {
            int idx = tid + i * 256;
            int k = idx / BN, n2 = idx % BN;
            Bs[k][n2] = B[(size_t)(k0 + k) * BN + n2];
        }
        __syncthreads();
#pragma unroll
        for (int kk = 0; kk < BK; ++kk) {
            float a[RPT], b[8];
#pragma unroll
            for (int r = 0; r < RPT; ++r) a[r] = As[kk][ty * RPT + r];
#pragma unroll
            for (int j = 0; j < 8; ++j) b[j] = Bs[kk][tx * 8 + j];
#pragma unroll
            for (int r = 0; r < RPT; ++r)
#pragma unroll
                for (int j = 0; j < 8; ++j) acc[r][j] += a[r] * b[j];
        }
        __syncthreads();
    }
    float bv[8];
#pragma unroll
    for (int j = 0; j < 8; ++j) {
        if constexpr (BIAS) bv[j] = bias[tx * 8 + j]; else bv[j] = 0.f;
    }
#pragma unroll
    for (int r = 0; r < RPT; ++r) {
        int gr = bm + ty * RPT + r;
        if (gr < M) {
#pragma unroll
            for (int j = 0; j < 8; ++j) {
                float v = acc[r][j] + bv[j];
                if constexpr (RELU) v = fmaxf(v, 0.f);
                C[(size_t)gr * BN + tx * 8 + j] = v;
            }
        }
    }
}

// ---------------- launch ----------------

extern "C" void kernel_launch(void* const* d_in, const int* in_sizes, int n_in,
                              void* d_out, int out_size, void* d_ws, size_t ws_size,
                              hipStream_t stream) {
    const float* x  = (const float*)d_in[0];
    const int*   ei = (const int*)d_in[1];
    const float* w1 = (const float*)d_in[2];
    const float* b1 = (const float*)d_in[3];
    const float* cw = (const float*)d_in[4];
    const float* w2 = (const float*)d_in[5];
    const float* b2 = (const float*)d_in[6];
    float* out = (float*)d_out;
    const int* rowp = ei;            // source nodes
    const int* colp = ei + N_EDGES;  // target nodes

    char* p = (char*)d_ws;
    auto alloc = [&](size_t bytes) -> void* {
        void* r = (void*)p;
        p += ((bytes + 255) / 256) * 256;
        return r;
    };
    int*   deg     = (int*)  alloc((size_t)N_NODES * 4);
    int*   cursor  = (int*)  alloc((size_t)N_NODES * 4);
    int*   offsets = (int*)  alloc((size_t)(N_NODES + 1) * 4);
    int*   srcA    = (int*)  alloc((size_t)N_EDGES * 4);
    float* wgt     = (float*)alloc((size_t)N_EDGES * 4);
    float* dinv    = (float*)alloc((size_t)N_NODES * 4);
    float* h0      = (float*)alloc((size_t)N_NODES * H_DIM * 4);
    float* h1      = (float*)alloc((size_t)N_NODES * H_DIM * 4);
    float* z       = (float*)alloc((size_t)N_NODES * H_DIM * 4);

    float* h2     = out;                              // output 0: h [N,128]
    float* logits = out + (size_t)N_NODES * H_DIM;    // output 1: [N,64]

    // CSC build
    hipLaunchKernelGGL(k_init,  dim3((N_NODES + 255) / 256), dim3(256), 0, stream, deg, cursor, N_NODES);
    hipLaunchKernelGGL(k_count, dim3((N_EDGES + 255) / 256), dim3(256), 0, stream, colp, deg, N_EDGES);
    hipLaunchKernelGGL(k_dinv,  dim3((N_NODES + 255) / 256), dim3(256), 0, stream, deg, dinv, N_NODES);
    hipLaunchKernelGGL(k_scan,  dim3(1), dim3(1024), 0, stream, deg, offsets, N_NODES);
    hipLaunchKernelGGL(k_fill,  dim3((N_EDGES + 255) / 256), dim3(256), 0, stream,
                       rowp, colp, offsets, cursor, dinv, srcA, wgt, N_EDGES);

    int gemmGrid = (N_NODES + 63) / 64;
    // h0 = relu(x @ w1 + b1)
    hipLaunchKernelGGL((k_gemm<128, true, true>), dim3(gemmGrid), dim3(256), 0, stream,
                       x, w1, b1, h0, N_NODES, D_IN);

    int aggGrid = (int)(((size_t)N_NODES * 64 + 255) / 256);
    // layer 0
    hipLaunchKernelGGL(k_agg, dim3(aggGrid), dim3(256), 0, stream,
                       h0, h0, offsets, srcA, wgt, dinv, z, N_NODES);
    hipLaunchKernelGGL((k_gemm<128, false, false>), dim3(gemmGrid), dim3(256), 0, stream,
                       z, cw, (const float*)nullptr, h1, N_NODES, H_DIM);
    // layer 1
    hipLaunchKernelGGL(k_agg, dim3(aggGrid), dim3(256), 0, stream,
                       h1, h0, offsets, srcA, wgt, dinv, z, N_NODES);
    hipLaunchKernelGGL((k_gemm<128, false, false>), dim3(gemmGrid), dim3(256), 0, stream,
                       z, cw + H_DIM * H_DIM, (const float*)nullptr, h2, N_NODES, H_DIM);
    // logits = h2 @ w2 + b2
    hipLaunchKernelGGL((k_gemm<64, false, true>), dim3(gemmGrid), dim3(256), 0, stream,
                       h2, w2, b2, logits, N_NODES, H_DIM);
}

// Round 2
// 857.152 us; speedup vs baseline: 1.3585x; 1.3585x over previous
//
#include <hip/hip_runtime.h>

constexpr int N_NODES = 100000;
constexpr int N_EDGES = 1600000;
constexpr int D_IN   = 512;
constexpr int H_DIM  = 128;
constexpr int D_OUT  = 64;
constexpr float ALPHA = 0.1f;

typedef __attribute__((ext_vector_type(4))) float f32x4;
typedef __attribute__((ext_vector_type(8))) short bf16x8;

__device__ __forceinline__ unsigned short f2bf(float f) {
    unsigned int u = __float_as_uint(f);
    u += 0x7fff + ((u >> 16) & 1);          // RNE
    return (unsigned short)(u >> 16);
}
__device__ __forceinline__ float bf2f(unsigned short b) {
    return __uint_as_float(((unsigned int)b) << 16);
}

// ---------------- CSC build ----------------

__global__ void k_init(int* __restrict__ deg, int* __restrict__ cursor, int n) {
    int i = blockIdx.x * blockDim.x + threadIdx.x;
    if (i < n) { deg[i] = 0; cursor[i] = 0; }
}

__global__ void k_count(const int* __restrict__ col, int* __restrict__ deg, int e) {
    int i = blockIdx.x * blockDim.x + threadIdx.x;
    if (i < e) atomicAdd(&deg[col[i]], 1);
}

__global__ void k_dinv(const int* __restrict__ deg, float* __restrict__ dinv, int n) {
    int i = blockIdx.x * blockDim.x + threadIdx.x;
    if (i < n) dinv[i] = rsqrtf((float)(deg[i] + 1));   // +1 self loop
}

__global__ __launch_bounds__(1024) void k_scan(const int* __restrict__ deg,
                                               int* __restrict__ offsets, int n) {
    __shared__ int sums[1024];
    int t = threadIdx.x;
    int chunk = (n + 1023) / 1024;
    int begin = t * chunk;
    int end = begin + chunk; if (end > n) end = n;
    int s = 0;
    for (int i = begin; i < end; ++i) s += deg[i];
    sums[t] = s;
    __syncthreads();
    for (int off = 1; off < 1024; off <<= 1) {
        int v = (t >= off) ? sums[t - off] : 0;
        __syncthreads();
        sums[t] += v;
        __syncthreads();
    }
    int run = (t == 0) ? 0 : sums[t - 1];
    for (int i = begin; i < end; ++i) { offsets[i] = run; run += deg[i]; }
    if (t == 1023) offsets[n] = run;
}

__global__ void k_fill(const int* __restrict__ row, const int* __restrict__ col,
                       const int* __restrict__ offsets, int* __restrict__ cursor,
                       const float* __restrict__ dinv,
                       int* __restrict__ srcA, float* __restrict__ wgt, int e) {
    int i = blockIdx.x * blockDim.x + threadIdx.x;
    if (i >= e) return;
    int r = row[i], c = col[i];
    int p = offsets[c] + atomicAdd(&cursor[c], 1);
    srcA[p] = r;
    wgt[p]  = dinv[r] * dinv[c];
}

// ---------------- aggregation: one wave per node, float2/lane ----------------

__global__ __launch_bounds__(256) void k_agg(const float* __restrict__ hcur,
        const float* __restrict__ h0,
        const int* __restrict__ offsets, const int* __restrict__ srcA,
        const float* __restrict__ wgt, const float* __restrict__ dinv,
        float* __restrict__ z, int n) {
    int wid  = (int)((blockIdx.x * (unsigned)blockDim.x + threadIdx.x) >> 6);
    int lane = threadIdx.x & 63;
    if (wid >= n) return;
    float di = dinv[wid];
    const float oma = 1.0f - ALPHA;
    int o0 = offsets[wid], o1 = offsets[wid + 1];
    float2 hc = ((const float2*)(hcur + (size_t)wid * H_DIM))[lane];
    float2 hz = ((const float2*)(h0   + (size_t)wid * H_DIM))[lane];
    float sw = oma * di * di;
    float2 acc;
    acc.x = sw * hc.x + ALPHA * hz.x;
    acc.y = sw * hc.y + ALPHA * hz.y;
    for (int p2 = o0; p2 < o1; ++p2) {
        int s = srcA[p2];
        float wv = oma * wgt[p2];
        float2 hs = ((const float2*)(hcur + (size_t)s * H_DIM))[lane];
        acc.x += wv * hs.x;
        acc.y += wv * hs.y;
    }
    ((float2*)(z + (size_t)wid * H_DIM))[lane] = acc;
}

// ---------------- weight prep: f32 [K][N] -> bf16 hi/lo transposed [N][K] ----------------

__global__ void k_wprep(const float* __restrict__ w, unsigned short* __restrict__ hi,
                        unsigned short* __restrict__ lo, int K, int Nn) {
    int i = blockIdx.x * blockDim.x + threadIdx.x;
    if (i >= K * Nn) return;
    int n = i / K, k = i % K;
    float v = w[(size_t)k * Nn + n];
    unsigned short h = f2bf(v);
    hi[i] = h;
    lo[i] = f2bf(v - bf2f(h));
}

// ---------------- split-bf16 MFMA GEMM ----------------
// C[M,BN] = act(A[M,K] @ B[K,BN] + bias); A f32 (converted in-kernel),
// B pre-transposed bf16 hi/lo [BN][K]. acc += Ah*Bh + Ah*Bl + Al*Bh (~f32 acc).

template<int BN, bool RELU, bool BIAS>
__global__ __launch_bounds__(256) void k_mfma_gemm(
        const float* __restrict__ A,
        const unsigned short* __restrict__ Bth,
        const unsigned short* __restrict__ Btl,
        const float* __restrict__ bias,
        float* __restrict__ C, int M, int K) {
    constexpr int BM = 128, BK = 64;
    constexpr int WN = BN / 2;       // per-wave cols (2x2 waves)
    constexpr int NF = WN / 16;      // 16x16 frags per wave in N
    __shared__ unsigned short Ah[BM * BK], Al[BM * BK];
    __shared__ unsigned short Bh[BN * BK], Bl[BN * BK];
    char* AhC = (char*)Ah; char* AlC = (char*)Al;
    char* BhC = (char*)Bh; char* BlC = (char*)Bl;
    const int tid = threadIdx.x;
    const int wave = tid >> 6, lane = tid & 63;
    const int wrow = wave >> 1, wcol = wave & 1;
    const int l15 = lane & 15, l4 = lane >> 4;
    const int bm = blockIdx.x * BM;

    f32x4 acc[4][NF];
#pragma unroll
    for (int mf = 0; mf < 4; ++mf)
#pragma unroll
        for (int nf = 0; nf < NF; ++nf) acc[mf][nf] = (f32x4){0.f, 0.f, 0.f, 0.f};

    for (int k0 = 0; k0 < K; k0 += BK) {
        // stage A: f32 -> hi/lo bf16, XOR-swizzled LDS
#pragma unroll
        for (int c = 0; c < (BM * 8) / 256; ++c) {
            int ch = tid + c * 256;          // chunk = 8 elems along K
            int m = ch >> 3, kc = ch & 7;
            int gr = bm + m;
            float v[8];
            if (gr < M) {
                const float4* src = (const float4*)(A + (size_t)gr * K + k0 + kc * 8);
                float4 a0 = src[0], a1 = src[1];
                v[0] = a0.x; v[1] = a0.y; v[2] = a0.z; v[3] = a0.w;
                v[4] = a1.x; v[5] = a1.y; v[6] = a1.z; v[7] = a1.w;
            } else {
#pragma unroll
                for (int j = 0; j < 8; ++j) v[j] = 0.f;
            }
            bf16x8 hv, lv;
#pragma unroll
            for (int j = 0; j < 8; ++j) {
                unsigned short h = f2bf(v[j]);
                hv[j] = (short)h;
                lv[j] = (short)f2bf(v[j] - bf2f(h));
            }
            int byte = ((m * BK + kc * 8) * 2) ^ ((m & 7) << 4);
            *(bf16x8*)(AhC + byte) = hv;
            *(bf16x8*)(AlC + byte) = lv;
        }
        // stage B (already bf16 hi/lo, [BN][K] row-major)
#pragma unroll
        for (int c = 0; c < (BN * 8) / 256; ++c) {
            int ch = tid + c * 256;
            int n = ch >> 3, kc = ch & 7;
            bf16x8 hv = *(const bf16x8*)(Bth + (size_t)n * K + k0 + kc * 8);
            bf16x8 lv = *(const bf16x8*)(Btl + (size_t)n * K + k0 + kc * 8);
            int byte = ((n * BK + kc * 8) * 2) ^ ((n & 7) << 4);
            *(bf16x8*)(BhC + byte) = hv;
            *(bf16x8*)(BlC + byte) = lv;
        }
        __syncthreads();
#pragma unroll
        for (int ks = 0; ks < 2; ++ks) {
            bf16x8 ah[4], al[4], bh[NF], bl[NF];
#pragma unroll
            for (int mf = 0; mf < 4; ++mf) {
                int row = wrow * 64 + mf * 16 + l15;
                int byte = ((row * BK + ks * 32 + l4 * 8) * 2) ^ ((row & 7) << 4);
                ah[mf] = *(const bf16x8*)(AhC + byte);
                al[mf] = *(const bf16x8*)(AlC + byte);
            }
#pragma unroll
            for (int nf = 0; nf < NF; ++nf) {
                int n = wcol * WN + nf * 16 + l15;
                int byte = ((n * BK + ks * 32 + l4 * 8) * 2) ^ ((n & 7) << 4);
                bh[nf] = *(const bf16x8*)(BhC + byte);
                bl[nf] = *(const bf16x8*)(BlC + byte);
            }
#pragma unroll
            for (int mf = 0; mf < 4; ++mf)
#pragma unroll
                for (int nf = 0; nf < NF; ++nf) {
                    acc[mf][nf] = __builtin_amdgcn_mfma_f32_16x16x32_bf16(ah[mf], bh[nf], acc[mf][nf], 0, 0, 0);
                    acc[mf][nf] = __builtin_amdgcn_mfma_f32_16x16x32_bf16(ah[mf], bl[nf], acc[mf][nf], 0, 0, 0);
                    acc[mf][nf] = __builtin_amdgcn_mfma_f32_16x16x32_bf16(al[mf], bh[nf], acc[mf][nf], 0, 0, 0);
                }
        }
        __syncthreads();
    }
    // epilogue: C/D layout col=lane&15, row=(lane>>4)*4+reg
#pragma unroll
    for (int mf = 0; mf < 4; ++mf) {
#pragma unroll
        for (int nf = 0; nf < NF; ++nf) {
            int col = wcol * WN + nf * 16 + l15;
            float bv = 0.f;
            if constexpr (BIAS) bv = bias[col];
#pragma unroll
            for (int r = 0; r < 4; ++r) {
                int grow = bm + wrow * 64 + mf * 16 + l4 * 4 + r;
                if (grow < M) {
                    float v = acc[mf][nf][r] + bv;
                    if constexpr (RELU) v = fmaxf(v, 0.f);
                    C[(size_t)grow * BN + col] = v;
                }
            }
        }
    }
}

// ---------------- launch ----------------

extern "C" void kernel_launch(void* const* d_in, const int* in_sizes, int n_in,
                              void* d_out, int out_size, void* d_ws, size_t ws_size,
                              hipStream_t stream) {
    const float* x  = (const float*)d_in[0];
    const int*   ei = (const int*)d_in[1];
    const float* w1 = (const float*)d_in[2];
    const float* b1 = (const float*)d_in[3];
    const float* cw = (const float*)d_in[4];
    const float* w2 = (const float*)d_in[5];
    const float* b2 = (const float*)d_in[6];
    float* out = (float*)d_out;
    const int* rowp = ei;            // source nodes
    const int* colp = ei + N_EDGES;  // target nodes

    char* p = (char*)d_ws;
    auto alloc = [&](size_t bytes) -> void* {
        void* r = (void*)p;
        p += ((bytes + 255) / 256) * 256;
        return r;
    };
    int*   deg     = (int*)  alloc((size_t)N_NODES * 4);
    int*   cursor  = (int*)  alloc((size_t)N_NODES * 4);
    int*   offsets = (int*)  alloc((size_t)(N_NODES + 1) * 4);
    int*   srcA    = (int*)  alloc((size_t)N_EDGES * 4);
    float* wgt     = (float*)alloc((size_t)N_EDGES * 4);
    float* dinv    = (float*)alloc((size_t)N_NODES * 4);
    float* h0      = (float*)alloc((size_t)N_NODES * H_DIM * 4);
    float* h1      = (float*)alloc((size_t)N_NODES * H_DIM * 4);
    float* z       = (float*)alloc((size_t)N_NODES * H_DIM * 4);
    unsigned short* w1th = (unsigned short*)alloc((size_t)H_DIM * D_IN * 2);
    unsigned short* w1tl = (unsigned short*)alloc((size_t)H_DIM * D_IN * 2);
    unsigned short* cwth = (unsigned short*)alloc((size_t)2 * H_DIM * H_DIM * 2);
    unsigned short* cwtl = (unsigned short*)alloc((size_t)2 * H_DIM * H_DIM * 2);
    unsigned short* w2th = (unsigned short*)alloc((size_t)D_OUT * H_DIM * 2);
    unsigned short* w2tl = (unsigned short*)alloc((size_t)D_OUT * H_DIM * 2);

    float* h2     = out;                              // output 0: h [N,128]
    float* logits = out + (size_t)N_NODES * H_DIM;    // output 1: [N,64]

    // CSC build
    hipLaunchKernelGGL(k_init,  dim3((N_NODES + 255) / 256), dim3(256), 0, stream, deg, cursor, N_NODES);
    hipLaunchKernelGGL(k_count, dim3((N_EDGES + 255) / 256), dim3(256), 0, stream, colp, deg, N_EDGES);
    hipLaunchKernelGGL(k_dinv,  dim3((N_NODES + 255) / 256), dim3(256), 0, stream, deg, dinv, N_NODES);
    hipLaunchKernelGGL(k_scan,  dim3(1), dim3(1024), 0, stream, deg, offsets, N_NODES);
    hipLaunchKernelGGL(k_fill,  dim3((N_EDGES + 255) / 256), dim3(256), 0, stream,
                       rowp, colp, offsets, cursor, dinv, srcA, wgt, N_EDGES);

    // weight prep (tiny)
    hipLaunchKernelGGL(k_wprep, dim3((D_IN * H_DIM + 255) / 256), dim3(256), 0, stream,
                       w1, w1th, w1tl, D_IN, H_DIM);
    hipLaunchKernelGGL(k_wprep, dim3((H_DIM * H_DIM + 255) / 256), dim3(256), 0, stream,
                       cw, cwth, cwtl, H_DIM, H_DIM);
    hipLaunchKernelGGL(k_wprep, dim3((H_DIM * H_DIM + 255) / 256), dim3(256), 0, stream,
                       cw + H_DIM * H_DIM, cwth + H_DIM * H_DIM, cwtl + H_DIM * H_DIM, H_DIM, H_DIM);
    hipLaunchKernelGGL(k_wprep, dim3((H_DIM * D_OUT + 255) / 256), dim3(256), 0, stream,
                       w2, w2th, w2tl, H_DIM, D_OUT);

    int gemmGrid = (N_NODES + 127) / 128;
    // h0 = relu(x @ w1 + b1)
    hipLaunchKernelGGL((k_mfma_gemm<128, true, true>), dim3(gemmGrid), dim3(256), 0, stream,
                       x, w1th, w1tl, b1, h0, N_NODES, D_IN);

    int aggGrid = (int)(((size_t)N_NODES * 64 + 255) / 256);
    // layer 0
    hipLaunchKernelGGL(k_agg, dim3(aggGrid), dim3(256), 0, stream,
                       h0, h0, offsets, srcA, wgt, dinv, z, N_NODES);
    hipLaunchKernelGGL((k_mfma_gemm<128, false, false>), dim3(gemmGrid), dim3(256), 0, stream,
                       z, cwth, cwtl, (const float*)nullptr, h1, N_NODES, H_DIM);
    // layer 1
    hipLaunchKernelGGL(k_agg, dim3(aggGrid), dim3(256), 0, stream,
                       h1, h0, offsets, srcA, wgt, dinv, z, N_NODES);
    hipLaunchKernelGGL((k_mfma_gemm<128, false, false>), dim3(gemmGrid), dim3(256), 0, stream,
                       z, cwth + H_DIM * H_DIM, cwtl + H_DIM * H_DIM, (const float*)nullptr, h2, N_NODES, H_DIM);
    // logits = h2 @ w2 + b2
    hipLaunchKernelGGL((k_mfma_gemm<64, false, true>), dim3(gemmGrid), dim3(256), 0, stream,
                       h2, w2th, w2tl, b2, logits, N_NODES, H_DIM);
}

// Round 3
// 685.480 us; speedup vs baseline: 1.6987x; 1.2504x over previous
//
#include <hip/hip_runtime.h>

constexpr int N_NODES = 100000;
constexpr int N_EDGES = 1600000;
constexpr int D_IN   = 512;
constexpr int H_DIM  = 128;
constexpr int D_OUT  = 64;
constexpr float ALPHA = 0.1f;

typedef __attribute__((ext_vector_type(4))) float f32x4;
typedef __attribute__((ext_vector_type(8))) short bf16x8;

__device__ __forceinline__ unsigned short f2bf(float f) {
    unsigned int u = __float_as_uint(f);
    u += 0x7fff + ((u >> 16) & 1);          // RNE
    return (unsigned short)(u >> 16);
}
__device__ __forceinline__ float bf2f(unsigned short b) {
    return __uint_as_float(((unsigned int)b) << 16);
}

// ---------------- CSC build ----------------

__global__ void k_init(int* __restrict__ deg, int* __restrict__ cursor, int n) {
    int i = blockIdx.x * blockDim.x + threadIdx.x;
    if (i < n) { deg[i] = 0; cursor[i] = 0; }
}

__global__ void k_count(const int* __restrict__ col, int* __restrict__ deg, int e) {
    int i = blockIdx.x * blockDim.x + threadIdx.x;
    if (i < e) atomicAdd(&deg[col[i]], 1);
}

__global__ void k_dinv(const int* __restrict__ deg, float* __restrict__ dinv, int n) {
    int i = blockIdx.x * blockDim.x + threadIdx.x;
    if (i < n) dinv[i] = rsqrtf((float)(deg[i] + 1));   // +1 self loop
}

__global__ __launch_bounds__(1024) void k_scan(const int* __restrict__ deg,
                                               int* __restrict__ offsets, int n) {
    __shared__ int sums[1024];
    int t = threadIdx.x;
    int chunk = (n + 1023) / 1024;
    int begin = t * chunk;
    int end = begin + chunk; if (end > n) end = n;
    int s = 0;
    for (int i = begin; i < end; ++i) s += deg[i];
    sums[t] = s;
    __syncthreads();
    for (int off = 1; off < 1024; off <<= 1) {
        int v = (t >= off) ? sums[t - off] : 0;
        __syncthreads();
        sums[t] += v;
        __syncthreads();
    }
    int run = (t == 0) ? 0 : sums[t - 1];
    for (int i = begin; i < end; ++i) { offsets[i] = run; run += deg[i]; }
    if (t == 1023) offsets[n] = run;
}

__global__ void k_fill(const int* __restrict__ row, const int* __restrict__ col,
                       const int* __restrict__ offsets, int* __restrict__ cursor,
                       const float* __restrict__ dinv,
                       int* __restrict__ srcA, float* __restrict__ wgt, int e) {
    int i = blockIdx.x * blockDim.x + threadIdx.x;
    if (i >= e) return;
    int r = row[i], c = col[i];
    int p = offsets[c] + atomicAdd(&cursor[c], 1);
    srcA[p] = r;
    wgt[p]  = dinv[r] * dinv[c];
}

// ---------------- aggregation: one wave per node, bf16 gather, 4x unroll ----------------
// z = (1-a) * (dinv_i^2 * hb[i] + sum_in norm * hb[src]) + a * h0[i]

__global__ __launch_bounds__(256) void k_agg(
        const unsigned short* __restrict__ hb,   // bf16 rows [N][128] (current h)
        const float* __restrict__ h0,            // f32 residual
        const int* __restrict__ offsets, const int* __restrict__ srcA,
        const float* __restrict__ wgt, const float* __restrict__ dinv,
        float* __restrict__ z, int n) {
    int wid  = (int)((blockIdx.x * (unsigned)blockDim.x + threadIdx.x) >> 6);
    int lane = threadIdx.x & 63;
    if (wid >= n) return;
    float di = dinv[wid];
    const float oma = 1.0f - ALPHA;
    int o0 = offsets[wid], o1 = offsets[wid + 1];
    ushort2 hc = ((const ushort2*)(hb + (size_t)wid * H_DIM))[lane];
    float2 hz = ((const float2*)(h0 + (size_t)wid * H_DIM))[lane];
    float sw = oma * di * di;
    float accx = sw * bf2f(hc.x) + ALPHA * hz.x;
    float accy = sw * bf2f(hc.y) + ALPHA * hz.y;
    int p2 = o0;
    for (; p2 + 4 <= o1; p2 += 4) {
        int s0 = srcA[p2], s1 = srcA[p2 + 1], s2 = srcA[p2 + 2], s3 = srcA[p2 + 3];
        ushort2 g0 = ((const ushort2*)(hb + (size_t)s0 * H_DIM))[lane];
        ushort2 g1 = ((const ushort2*)(hb + (size_t)s1 * H_DIM))[lane];
        ushort2 g2 = ((const ushort2*)(hb + (size_t)s2 * H_DIM))[lane];
        ushort2 g3 = ((const ushort2*)(hb + (size_t)s3 * H_DIM))[lane];
        float w0 = oma * wgt[p2],     w1 = oma * wgt[p2 + 1];
        float w2 = oma * wgt[p2 + 2], w3 = oma * wgt[p2 + 3];
        accx += w0 * bf2f(g0.x); accy += w0 * bf2f(g0.y);
        accx += w1 * bf2f(g1.x); accy += w1 * bf2f(g1.y);
        accx += w2 * bf2f(g2.x); accy += w2 * bf2f(g2.y);
        accx += w3 * bf2f(g3.x); accy += w3 * bf2f(g3.y);
    }
    for (; p2 < o1; ++p2) {
        int s = srcA[p2];
        float wv = oma * wgt[p2];
        ushort2 g = ((const ushort2*)(hb + (size_t)s * H_DIM))[lane];
        accx += wv * bf2f(g.x); accy += wv * bf2f(g.y);
    }
    float2 o; o.x = accx; o.y = accy;
    ((float2*)(z + (size_t)wid * H_DIM))[lane] = o;
}

// ---------------- weight prep: f32 [K][N] -> bf16 hi/lo transposed [N][K] ----------------

__global__ void k_wprep(const float* __restrict__ w, unsigned short* __restrict__ hi,
                        unsigned short* __restrict__ lo, int K, int Nn) {
    int i = blockIdx.x * blockDim.x + threadIdx.x;
    if (i >= K * Nn) return;
    int n = i / K, k = i % K;
    float v = w[(size_t)k * Nn + n];
    unsigned short h = f2bf(v);
    hi[i] = h;
    lo[i] = f2bf(v - bf2f(h));
}

// ---------------- split-bf16 MFMA GEMM ----------------
// C = act(A @ B + bias); A f32 (converted in-kernel), B pre-transposed bf16 hi/lo [BN][K].
// acc += Ah*Bh + Ah*Bl + Al*Bh (~f32 accuracy). Optional f32 and/or bf16 output.

template<int BN, bool RELU, bool BIAS, bool WF32, bool WB16>
__global__ __launch_bounds__(256) void k_mfma_gemm(
        const float* __restrict__ A,
        const unsigned short* __restrict__ Bth,
        const unsigned short* __restrict__ Btl,
        const float* __restrict__ bias,
        float* __restrict__ C, unsigned short* __restrict__ Cb,
        int M, int K) {
    constexpr int BM = 128, BK = 64;
    constexpr int WN = BN / 2;       // per-wave cols (2x2 waves)
    constexpr int NF = WN / 16;      // 16x16 frags per wave in N
    __shared__ unsigned short Ah[BM * BK], Al[BM * BK];
    __shared__ unsigned short Bh[BN * BK], Bl[BN * BK];
    char* AhC = (char*)Ah; char* AlC = (char*)Al;
    char* BhC = (char*)Bh; char* BlC = (char*)Bl;
    const int tid = threadIdx.x;
    const int wave = tid >> 6, lane = tid & 63;
    const int wrow = wave >> 1, wcol = wave & 1;
    const int l15 = lane & 15, l4 = lane >> 4;
    const int bm = blockIdx.x * BM;

    f32x4 acc[4][NF];
#pragma unroll
    for (int mf = 0; mf < 4; ++mf)
#pragma unroll
        for (int nf = 0; nf < NF; ++nf) acc[mf][nf] = (f32x4){0.f, 0.f, 0.f, 0.f};

    for (int k0 = 0; k0 < K; k0 += BK) {
        // stage A: f32 -> hi/lo bf16, XOR-swizzled LDS
#pragma unroll
        for (int c = 0; c < (BM * 8) / 256; ++c) {
            int ch = tid + c * 256;          // chunk = 8 elems along K
            int m = ch >> 3, kc = ch & 7;
            int gr = bm + m;
            float v[8];
            if (gr < M) {
                const float4* src = (const float4*)(A + (size_t)gr * K + k0 + kc * 8);
                float4 a0 = src[0], a1 = src[1];
                v[0] = a0.x; v[1] = a0.y; v[2] = a0.z; v[3] = a0.w;
                v[4] = a1.x; v[5] = a1.y; v[6] = a1.z; v[7] = a1.w;
            } else {
#pragma unroll
                for (int j = 0; j < 8; ++j) v[j] = 0.f;
            }
            bf16x8 hv, lv;
#pragma unroll
            for (int j = 0; j < 8; ++j) {
                unsigned short h = f2bf(v[j]);
                hv[j] = (short)h;
                lv[j] = (short)f2bf(v[j] - bf2f(h));
            }
            int byte = ((m * BK + kc * 8) * 2) ^ ((m & 7) << 4);
            *(bf16x8*)(AhC + byte) = hv;
            *(bf16x8*)(AlC + byte) = lv;
        }
        // stage B (already bf16 hi/lo, [BN][K] row-major)
#pragma unroll
        for (int c = 0; c < (BN * 8) / 256; ++c) {
            int ch = tid + c * 256;
            int n = ch >> 3, kc = ch & 7;
            bf16x8 hv = *(const bf16x8*)(Bth + (size_t)n * K + k0 + kc * 8);
            bf16x8 lv = *(const bf16x8*)(Btl + (size_t)n * K + k0 + kc * 8);
            int byte = ((n * BK + kc * 8) * 2) ^ ((n & 7) << 4);
            *(bf16x8*)(BhC + byte) = hv;
            *(bf16x8*)(BlC + byte) = lv;
        }
        __syncthreads();
#pragma unroll
        for (int ks = 0; ks < 2; ++ks) {
            bf16x8 ah[4], al[4], bh[NF], bl[NF];
#pragma unroll
            for (int mf = 0; mf < 4; ++mf) {
                int row = wrow * 64 + mf * 16 + l15;
                int byte = ((row * BK + ks * 32 + l4 * 8) * 2) ^ ((row & 7) << 4);
                ah[mf] = *(const bf16x8*)(AhC + byte);
                al[mf] = *(const bf16x8*)(AlC + byte);
            }
#pragma unroll
            for (int nf = 0; nf < NF; ++nf) {
                int n = wcol * WN + nf * 16 + l15;
                int byte = ((n * BK + ks * 32 + l4 * 8) * 2) ^ ((n & 7) << 4);
                bh[nf] = *(const bf16x8*)(BhC + byte);
                bl[nf] = *(const bf16x8*)(BlC + byte);
            }
#pragma unroll
            for (int mf = 0; mf < 4; ++mf)
#pragma unroll
                for (int nf = 0; nf < NF; ++nf) {
                    acc[mf][nf] = __builtin_amdgcn_mfma_f32_16x16x32_bf16(ah[mf], bh[nf], acc[mf][nf], 0, 0, 0);
                    acc[mf][nf] = __builtin_amdgcn_mfma_f32_16x16x32_bf16(ah[mf], bl[nf], acc[mf][nf], 0, 0, 0);
                    acc[mf][nf] = __builtin_amdgcn_mfma_f32_16x16x32_bf16(al[mf], bh[nf], acc[mf][nf], 0, 0, 0);
                }
        }
        __syncthreads();
    }
    // epilogue: C/D layout col=lane&15, row=(lane>>4)*4+reg
#pragma unroll
    for (int mf = 0; mf < 4; ++mf) {
#pragma unroll
        for (int nf = 0; nf < NF; ++nf) {
            int col = wcol * WN + nf * 16 + l15;
            float bv = 0.f;
            if constexpr (BIAS) bv = bias[col];
#pragma unroll
            for (int r = 0; r < 4; ++r) {
                int grow = bm + wrow * 64 + mf * 16 + l4 * 4 + r;
                if (grow < M) {
                    float v = acc[mf][nf][r] + bv;
                    if constexpr (RELU) v = fmaxf(v, 0.f);
                    if constexpr (WF32) C[(size_t)grow * BN + col] = v;
                    if constexpr (WB16) Cb[(size_t)grow * BN + col] = f2bf(v);
                }
            }
        }
    }
}

// ---------------- launch ----------------

extern "C" void kernel_launch(void* const* d_in, const int* in_sizes, int n_in,
                              void* d_out, int out_size, void* d_ws, size_t ws_size,
                              hipStream_t stream) {
    const float* x  = (const float*)d_in[0];
    const int*   ei = (const int*)d_in[1];
    const float* w1 = (const float*)d_in[2];
    const float* b1 = (const float*)d_in[3];
    const float* cw = (const float*)d_in[4];
    const float* w2 = (const float*)d_in[5];
    const float* b2 = (const float*)d_in[6];
    float* out = (float*)d_out;
    const int* rowp = ei;            // source nodes
    const int* colp = ei + N_EDGES;  // target nodes

    char* p = (char*)d_ws;
    auto alloc = [&](size_t bytes) -> void* {
        void* r = (void*)p;
        p += ((bytes + 255) / 256) * 256;
        return r;
    };
    int*   deg     = (int*)  alloc((size_t)N_NODES * 4);
    int*   cursor  = (int*)  alloc((size_t)N_NODES * 4);
    int*   offsets = (int*)  alloc((size_t)(N_NODES + 1) * 4);
    int*   srcA    = (int*)  alloc((size_t)N_EDGES * 4);
    float* wgt     = (float*)alloc((size_t)N_EDGES * 4);
    float* dinv    = (float*)alloc((size_t)N_NODES * 4);
    float* h0      = (float*)alloc((size_t)N_NODES * H_DIM * 4);
    float* z       = (float*)alloc((size_t)N_NODES * H_DIM * 4);
    unsigned short* h0b = (unsigned short*)alloc((size_t)N_NODES * H_DIM * 2);
    unsigned short* h1b = (unsigned short*)alloc((size_t)N_NODES * H_DIM * 2);
    unsigned short* w1th = (unsigned short*)alloc((size_t)H_DIM * D_IN * 2);
    unsigned short* w1tl = (unsigned short*)alloc((size_t)H_DIM * D_IN * 2);
    unsigned short* cwth = (unsigned short*)alloc((size_t)2 * H_DIM * H_DIM * 2);
    unsigned short* cwtl = (unsigned short*)alloc((size_t)2 * H_DIM * H_DIM * 2);
    unsigned short* w2th = (unsigned short*)alloc((size_t)D_OUT * H_DIM * 2);
    unsigned short* w2tl = (unsigned short*)alloc((size_t)D_OUT * H_DIM * 2);

    float* h2     = out;                              // output 0: h [N,128]
    float* logits = out + (size_t)N_NODES * H_DIM;    // output 1: [N,64]

    // CSC build
    hipLaunchKernelGGL(k_init,  dim3((N_NODES + 255) / 256), dim3(256), 0, stream, deg, cursor, N_NODES);
    hipLaunchKernelGGL(k_count, dim3((N_EDGES + 255) / 256), dim3(256), 0, stream, colp, deg, N_EDGES);
    hipLaunchKernelGGL(k_dinv,  dim3((N_NODES + 255) / 256), dim3(256), 0, stream, deg, dinv, N_NODES);
    hipLaunchKernelGGL(k_scan,  dim3(1), dim3(1024), 0, stream, deg, offsets, N_NODES);
    hipLaunchKernelGGL(k_fill,  dim3((N_EDGES + 255) / 256), dim3(256), 0, stream,
                       rowp, colp, offsets, cursor, dinv, srcA, wgt, N_EDGES);

    // weight prep (tiny)
    hipLaunchKernelGGL(k_wprep, dim3((D_IN * H_DIM + 255) / 256), dim3(256), 0, stream,
                       w1, w1th, w1tl, D_IN, H_DIM);
    hipLaunchKernelGGL(k_wprep, dim3((H_DIM * H_DIM + 255) / 256), dim3(256), 0, stream,
                       cw, cwth, cwtl, H_DIM, H_DIM);
    hipLaunchKernelGGL(k_wprep, dim3((H_DIM * H_DIM + 255) / 256), dim3(256), 0, stream,
                       cw + H_DIM * H_DIM, cwth + H_DIM * H_DIM, cwtl + H_DIM * H_DIM, H_DIM, H_DIM);
    hipLaunchKernelGGL(k_wprep, dim3((H_DIM * D_OUT + 255) / 256), dim3(256), 0, stream,
                       w2, w2th, w2tl, H_DIM, D_OUT);

    int gemmGrid = (N_NODES + 127) / 128;
    // h0 = relu(x @ w1 + b1): f32 + bf16 copies
    hipLaunchKernelGGL((k_mfma_gemm<128, true, true, true, true>), dim3(gemmGrid), dim3(256), 0, stream,
                       x, w1th, w1tl, b1, h0, h0b, N_NODES, D_IN);

    int aggGrid = (int)(((size_t)N_NODES * 64 + 255) / 256);
    // layer 0
    hipLaunchKernelGGL(k_agg, dim3(aggGrid), dim3(256), 0, stream,
                       h0b, h0, offsets, srcA, wgt, dinv, z, N_NODES);
    hipLaunchKernelGGL((k_mfma_gemm<128, false, false, false, true>), dim3(gemmGrid), dim3(256), 0, stream,
                       z, cwth, cwtl, (const float*)nullptr, (float*)nullptr, h1b, N_NODES, H_DIM);
    // layer 1
    hipLaunchKernelGGL(k_agg, dim3(aggGrid), dim3(256), 0, stream,
                       h1b, h0, offsets, srcA, wgt, dinv, z, N_NODES);
    hipLaunchKernelGGL((k_mfma_gemm<128, false, false, true, false>), dim3(gemmGrid), dim3(256), 0, stream,
                       z, cwth + H_DIM * H_DIM, cwtl + H_DIM * H_DIM, (const float*)nullptr, h2,
                       (unsigned short*)nullptr, N_NODES, H_DIM);
    // logits = h2 @ w2 + b2
    hipLaunchKernelGGL((k_mfma_gemm<64, false, true, true, false>), dim3(gemmGrid), dim3(256), 0, stream,
                       h2, w2th, w2tl, b2, logits, (unsigned short*)nullptr, N_NODES, H_DIM);
}

// Round 4
// 536.936 us; speedup vs baseline: 2.1686x; 1.2766x over previous
//
#include <hip/hip_runtime.h>

constexpr int N_NODES = 100000;
constexpr int N_EDGES = 1600000;
constexpr int D_IN   = 512;
constexpr int H_DIM  = 128;
constexpr int D_OUT  = 64;
constexpr float ALPHA = 0.1f;

constexpr int SCAN_TPB = 256;                 // threads per scan block
constexpr int SCAN_EPB = SCAN_TPB * 8;        // 2048 elems per block
constexpr int SCAN_NB  = (N_NODES + SCAN_EPB - 1) / SCAN_EPB;   // 49

typedef __attribute__((ext_vector_type(4))) float f32x4;
typedef __attribute__((ext_vector_type(8))) short bf16x8;

__device__ __forceinline__ unsigned short f2bf(float f) {
    unsigned int u = __float_as_uint(f);
    u += 0x7fff + ((u >> 16) & 1);          // RNE
    return (unsigned short)(u >> 16);
}
__device__ __forceinline__ float bf2f(unsigned short b) {
    return __uint_as_float(((unsigned int)b) << 16);
}

// ---------------- CSC build ----------------

__global__ void k_init(int* __restrict__ deg, int* __restrict__ cursor, int n) {
    int i = blockIdx.x * blockDim.x + threadIdx.x;
    if (i < n) { deg[i] = 0; cursor[i] = 0; }
}

__global__ void k_count(const int* __restrict__ col, int* __restrict__ deg, int e) {
    int i = blockIdx.x * blockDim.x + threadIdx.x;
    if (i < e) atomicAdd(&deg[col[i]], 1);
}

__global__ void k_dinv(const int* __restrict__ deg, float* __restrict__ dinv, int n) {
    int i = blockIdx.x * blockDim.x + threadIdx.x;
    if (i < n) dinv[i] = rsqrtf((float)(deg[i] + 1));   // +1 self loop
}

// ---- 3-phase hierarchical exclusive scan of deg -> offsets ----

__global__ __launch_bounds__(SCAN_TPB) void k_scan_part(const int* __restrict__ deg,
                                                        int* __restrict__ partials, int n) {
    __shared__ int red[SCAN_TPB];
    int t = threadIdx.x;
    int base = blockIdx.x * SCAN_EPB + t * 8;
    int s = 0;
    if (base + 8 <= n) {
        int4 a = *(const int4*)(deg + base);
        int4 b = *(const int4*)(deg + base + 4);
        s = a.x + a.y + a.z + a.w + b.x + b.y + b.z + b.w;
    } else {
        for (int j = 0; j < 8; ++j) if (base + j < n) s += deg[base + j];
    }
    red[t] = s;
    __syncthreads();
    for (int off = SCAN_TPB / 2; off > 0; off >>= 1) {
        if (t < off) red[t] += red[t + off];
        __syncthreads();
    }
    if (t == 0) partials[blockIdx.x] = red[0];
}

__global__ __launch_bounds__(64) void k_scan_mid(int* __restrict__ partials,
                                                 int* __restrict__ offsets) {
    __shared__ int buf[SCAN_NB];
    int t = threadIdx.x;
    if (t < SCAN_NB) buf[t] = partials[t];
    __syncthreads();
    if (t == 0) {
        int run = 0;
        for (int i = 0; i < SCAN_NB; ++i) { int v = buf[i]; buf[i] = run; run += v; }
        offsets[N_NODES] = run;    // == E
    }
    __syncthreads();
    if (t < SCAN_NB) partials[t] = buf[t];
}

__global__ __launch_bounds__(SCAN_TPB) void k_scan_write(const int* __restrict__ deg,
                                                         const int* __restrict__ partials,
                                                         int* __restrict__ offsets, int n) {
    __shared__ int sums[SCAN_TPB];
    int t = threadIdx.x;
    int base = blockIdx.x * SCAN_EPB + t * 8;
    int v[8];
    if (base + 8 <= n) {
        int4 a = *(const int4*)(deg + base);
        int4 b = *(const int4*)(deg + base + 4);
        v[0] = a.x; v[1] = a.y; v[2] = a.z; v[3] = a.w;
        v[4] = b.x; v[5] = b.y; v[6] = b.z; v[7] = b.w;
    } else {
        for (int j = 0; j < 8; ++j) v[j] = (base + j < n) ? deg[base + j] : 0;
    }
    int p[8], s = 0;
#pragma unroll
    for (int j = 0; j < 8; ++j) { p[j] = s; s += v[j]; }
    sums[t] = s;
    __syncthreads();
    // Hillis-Steele inclusive scan over thread sums
    for (int off = 1; off < SCAN_TPB; off <<= 1) {
        int add = (t >= off) ? sums[t - off] : 0;
        __syncthreads();
        sums[t] += add;
        __syncthreads();
    }
    int tbase = partials[blockIdx.x] + ((t == 0) ? 0 : sums[t - 1]);
#pragma unroll
    for (int j = 0; j < 8; ++j)
        if (base + j < n) offsets[base + j] = tbase + p[j];
}

__global__ void k_fill(const int* __restrict__ row, const int* __restrict__ col,
                       const int* __restrict__ offsets, int* __restrict__ cursor,
                       const float* __restrict__ dinv,
                       int* __restrict__ srcA, float* __restrict__ wgt, int e) {
    int i = blockIdx.x * blockDim.x + threadIdx.x;
    if (i >= e) return;
    int r = row[i], c = col[i];
    int p = offsets[c] + atomicAdd(&cursor[c], 1);
    srcA[p] = r;
    wgt[p]  = dinv[r] * dinv[c];
}

// ---------------- aggregation: one wave per node, bf16 gather, 4x unroll ----------------
// z = (1-a) * (dinv_i^2 * hb[i] + sum_in norm * hb[src]) + a * h0[i]

__global__ __launch_bounds__(256) void k_agg(
        const unsigned short* __restrict__ hb,   // bf16 rows [N][128] (current h)
        const float* __restrict__ h0,            // f32 residual
        const int* __restrict__ offsets, const int* __restrict__ srcA,
        const float* __restrict__ wgt, const float* __restrict__ dinv,
        float* __restrict__ z, int n) {
    int wid  = (int)((blockIdx.x * (unsigned)blockDim.x + threadIdx.x) >> 6);
    int lane = threadIdx.x & 63;
    if (wid >= n) return;
    float di = dinv[wid];
    const float oma = 1.0f - ALPHA;
    int o0 = offsets[wid], o1 = offsets[wid + 1];
    ushort2 hc = ((const ushort2*)(hb + (size_t)wid * H_DIM))[lane];
    float2 hz = ((const float2*)(h0 + (size_t)wid * H_DIM))[lane];
    float sw = oma * di * di;
    float accx = sw * bf2f(hc.x) + ALPHA * hz.x;
    float accy = sw * bf2f(hc.y) + ALPHA * hz.y;
    int p2 = o0;
    for (; p2 + 4 <= o1; p2 += 4) {
        int s0 = srcA[p2], s1 = srcA[p2 + 1], s2 = srcA[p2 + 2], s3 = srcA[p2 + 3];
        ushort2 g0 = ((const ushort2*)(hb + (size_t)s0 * H_DIM))[lane];
        ushort2 g1 = ((const ushort2*)(hb + (size_t)s1 * H_DIM))[lane];
        ushort2 g2 = ((const ushort2*)(hb + (size_t)s2 * H_DIM))[lane];
        ushort2 g3 = ((const ushort2*)(hb + (size_t)s3 * H_DIM))[lane];
        float w0 = oma * wgt[p2],     w1 = oma * wgt[p2 + 1];
        float w2 = oma * wgt[p2 + 2], w3 = oma * wgt[p2 + 3];
        accx += w0 * bf2f(g0.x); accy += w0 * bf2f(g0.y);
        accx += w1 * bf2f(g1.x); accy += w1 * bf2f(g1.y);
        accx += w2 * bf2f(g2.x); accy += w2 * bf2f(g2.y);
        accx += w3 * bf2f(g3.x); accy += w3 * bf2f(g3.y);
    }
    for (; p2 < o1; ++p2) {
        int s = srcA[p2];
        float wv = oma * wgt[p2];
        ushort2 g = ((const ushort2*)(hb + (size_t)s * H_DIM))[lane];
        accx += wv * bf2f(g.x); accy += wv * bf2f(g.y);
    }
    float2 o; o.x = accx; o.y = accy;
    ((float2*)(z + (size_t)wid * H_DIM))[lane] = o;
}

// ---------------- weight prep: f32 [K][N] -> bf16 hi/lo transposed [N][K] ----------------

__global__ void k_wprep(const float* __restrict__ w, unsigned short* __restrict__ hi,
                        unsigned short* __restrict__ lo, int K, int Nn) {
    int i = blockIdx.x * blockDim.x + threadIdx.x;
    if (i >= K * Nn) return;
    int n = i / K, k = i % K;
    float v = w[(size_t)k * Nn + n];
    unsigned short h = f2bf(v);
    hi[i] = h;
    lo[i] = f2bf(v - bf2f(h));
}

// ---------------- split-bf16 MFMA GEMM ----------------
// C = act(A @ B + bias); A f32 (converted in-kernel), B pre-transposed bf16 hi/lo [BN][K].
// acc += Ah*Bh + Ah*Bl + Al*Bh (~f32 accuracy). Optional f32 and/or bf16 output.

template<int BN, bool RELU, bool BIAS, bool WF32, bool WB16>
__global__ __launch_bounds__(256) void k_mfma_gemm(
        const float* __restrict__ A,
        const unsigned short* __restrict__ Bth,
        const unsigned short* __restrict__ Btl,
        const float* __restrict__ bias,
        float* __restrict__ C, unsigned short* __restrict__ Cb,
        int M, int K) {
    constexpr int BM = 128, BK = 64;
    constexpr int WN = BN / 2;       // per-wave cols (2x2 waves)
    constexpr int NF = WN / 16;      // 16x16 frags per wave in N
    __shared__ unsigned short Ah[BM * BK], Al[BM * BK];
    __shared__ unsigned short Bh[BN * BK], Bl[BN * BK];
    char* AhC = (char*)Ah; char* AlC = (char*)Al;
    char* BhC = (char*)Bh; char* BlC = (char*)Bl;
    const int tid = threadIdx.x;
    const int wave = tid >> 6, lane = tid & 63;
    const int wrow = wave >> 1, wcol = wave & 1;
    const int l15 = lane & 15, l4 = lane >> 4;
    const int bm = blockIdx.x * BM;

    f32x4 acc[4][NF];
#pragma unroll
    for (int mf = 0; mf < 4; ++mf)
#pragma unroll
        for (int nf = 0; nf < NF; ++nf) acc[mf][nf] = (f32x4){0.f, 0.f, 0.f, 0.f};

    for (int k0 = 0; k0 < K; k0 += BK) {
        // stage A: f32 -> hi/lo bf16, XOR-swizzled LDS
#pragma unroll
        for (int c = 0; c < (BM * 8) / 256; ++c) {
            int ch = tid + c * 256;          // chunk = 8 elems along K
            int m = ch >> 3, kc = ch & 7;
            int gr = bm + m;
            float v[8];
            if (gr < M) {
                const float4* src = (const float4*)(A + (size_t)gr * K + k0 + kc * 8);
                float4 a0 = src[0], a1 = src[1];
                v[0] = a0.x; v[1] = a0.y; v[2] = a0.z; v[3] = a0.w;
                v[4] = a1.x; v[5] = a1.y; v[6] = a1.z; v[7] = a1.w;
            } else {
#pragma unroll
                for (int j = 0; j < 8; ++j) v[j] = 0.f;
            }
            bf16x8 hv, lv;
#pragma unroll
            for (int j = 0; j < 8; ++j) {
                unsigned short h = f2bf(v[j]);
                hv[j] = (short)h;
                lv[j] = (short)f2bf(v[j] - bf2f(h));
            }
            int byte = ((m * BK + kc * 8) * 2) ^ ((m & 7) << 4);
            *(bf16x8*)(AhC + byte) = hv;
            *(bf16x8*)(AlC + byte) = lv;
        }
        // stage B (already bf16 hi/lo, [BN][K] row-major)
#pragma unroll
        for (int c = 0; c < (BN * 8) / 256; ++c) {
            int ch = tid + c * 256;
            int n = ch >> 3, kc = ch & 7;
            bf16x8 hv = *(const bf16x8*)(Bth + (size_t)n * K + k0 + kc * 8);
            bf16x8 lv = *(const bf16x8*)(Btl + (size_t)n * K + k0 + kc * 8);
            int byte = ((n * BK + kc * 8) * 2) ^ ((n & 7) << 4);
            *(bf16x8*)(BhC + byte) = hv;
            *(bf16x8*)(BlC + byte) = lv;
        }
        __syncthreads();
#pragma unroll
        for (int ks = 0; ks < 2; ++ks) {
            bf16x8 ah[4], al[4], bh[NF], bl[NF];
#pragma unroll
            for (int mf = 0; mf < 4; ++mf) {
                int row = wrow * 64 + mf * 16 + l15;
                int byte = ((row * BK + ks * 32 + l4 * 8) * 2) ^ ((row & 7) << 4);
                ah[mf] = *(const bf16x8*)(AhC + byte);
                al[mf] = *(const bf16x8*)(AlC + byte);
            }
#pragma unroll
            for (int nf = 0; nf < NF; ++nf) {
                int n = wcol * WN + nf * 16 + l15;
                int byte = ((n * BK + ks * 32 + l4 * 8) * 2) ^ ((n & 7) << 4);
                bh[nf] = *(const bf16x8*)(BhC + byte);
                bl[nf] = *(const bf16x8*)(BlC + byte);
            }
#pragma unroll
            for (int mf = 0; mf < 4; ++mf)
#pragma unroll
                for (int nf = 0; nf < NF; ++nf) {
                    acc[mf][nf] = __builtin_amdgcn_mfma_f32_16x16x32_bf16(ah[mf], bh[nf], acc[mf][nf], 0, 0, 0);
                    acc[mf][nf] = __builtin_amdgcn_mfma_f32_16x16x32_bf16(ah[mf], bl[nf], acc[mf][nf], 0, 0, 0);
                    acc[mf][nf] = __builtin_amdgcn_mfma_f32_16x16x32_bf16(al[mf], bh[nf], acc[mf][nf], 0, 0, 0);
                }
        }
        __syncthreads();
    }
    // epilogue: C/D layout col=lane&15, row=(lane>>4)*4+reg
#pragma unroll
    for (int mf = 0; mf < 4; ++mf) {
#pragma unroll
        for (int nf = 0; nf < NF; ++nf) {
            int col = wcol * WN + nf * 16 + l15;
            float bv = 0.f;
            if constexpr (BIAS) bv = bias[col];
#pragma unroll
            for (int r = 0; r < 4; ++r) {
                int grow = bm + wrow * 64 + mf * 16 + l4 * 4 + r;
                if (grow < M) {
                    float v = acc[mf][nf][r] + bv;
                    if constexpr (RELU) v = fmaxf(v, 0.f);
                    if constexpr (WF32) C[(size_t)grow * BN + col] = v;
                    if constexpr (WB16) Cb[(size_t)grow * BN + col] = f2bf(v);
                }
            }
        }
    }
}

// ---------------- launch ----------------

extern "C" void kernel_launch(void* const* d_in, const int* in_sizes, int n_in,
                              void* d_out, int out_size, void* d_ws, size_t ws_size,
                              hipStream_t stream) {
    const float* x  = (const float*)d_in[0];
    const int*   ei = (const int*)d_in[1];
    const float* w1 = (const float*)d_in[2];
    const float* b1 = (const float*)d_in[3];
    const float* cw = (const float*)d_in[4];
    const float* w2 = (const float*)d_in[5];
    const float* b2 = (const float*)d_in[6];
    float* out = (float*)d_out;
    const int* rowp = ei;            // source nodes
    const int* colp = ei + N_EDGES;  // target nodes

    char* p = (char*)d_ws;
    auto alloc = [&](size_t bytes) -> void* {
        void* r = (void*)p;
        p += ((bytes + 255) / 256) * 256;
        return r;
    };
    int*   deg     = (int*)  alloc((size_t)N_NODES * 4);
    int*   cursor  = (int*)  alloc((size_t)N_NODES * 4);
    int*   offsets = (int*)  alloc((size_t)(N_NODES + 1) * 4);
    int*   partials= (int*)  alloc((size_t)SCAN_NB * 4);
    int*   srcA    = (int*)  alloc((size_t)N_EDGES * 4);
    float* wgt     = (float*)alloc((size_t)N_EDGES * 4);
    float* dinv    = (float*)alloc((size_t)N_NODES * 4);
    float* h0      = (float*)alloc((size_t)N_NODES * H_DIM * 4);
    float* z       = (float*)alloc((size_t)N_NODES * H_DIM * 4);
    unsigned short* h0b = (unsigned short*)alloc((size_t)N_NODES * H_DIM * 2);
    unsigned short* h1b = (unsigned short*)alloc((size_t)N_NODES * H_DIM * 2);
    unsigned short* w1th = (unsigned short*)alloc((size_t)H_DIM * D_IN * 2);
    unsigned short* w1tl = (unsigned short*)alloc((size_t)H_DIM * D_IN * 2);
    unsigned short* cwth = (unsigned short*)alloc((size_t)2 * H_DIM * H_DIM * 2);
    unsigned short* cwtl = (unsigned short*)alloc((size_t)2 * H_DIM * H_DIM * 2);
    unsigned short* w2th = (unsigned short*)alloc((size_t)D_OUT * H_DIM * 2);
    unsigned short* w2tl = (unsigned short*)alloc((size_t)D_OUT * H_DIM * 2);

    float* h2     = out;                              // output 0: h [N,128]
    float* logits = out + (size_t)N_NODES * H_DIM;    // output 1: [N,64]

    // CSC build
    hipLaunchKernelGGL(k_init,  dim3((N_NODES + 255) / 256), dim3(256), 0, stream, deg, cursor, N_NODES);
    hipLaunchKernelGGL(k_count, dim3((N_EDGES + 255) / 256), dim3(256), 0, stream, colp, deg, N_EDGES);
    hipLaunchKernelGGL(k_dinv,  dim3((N_NODES + 255) / 256), dim3(256), 0, stream, deg, dinv, N_NODES);
    hipLaunchKernelGGL(k_scan_part,  dim3(SCAN_NB), dim3(SCAN_TPB), 0, stream, deg, partials, N_NODES);
    hipLaunchKernelGGL(k_scan_mid,   dim3(1), dim3(64), 0, stream, partials, offsets);
    hipLaunchKernelGGL(k_scan_write, dim3(SCAN_NB), dim3(SCAN_TPB), 0, stream, deg, partials, offsets, N_NODES);
    hipLaunchKernelGGL(k_fill,  dim3((N_EDGES + 255) / 256), dim3(256), 0, stream,
                       rowp, colp, offsets, cursor, dinv, srcA, wgt, N_EDGES);

    // weight prep (tiny)
    hipLaunchKernelGGL(k_wprep, dim3((D_IN * H_DIM + 255) / 256), dim3(256), 0, stream,
                       w1, w1th, w1tl, D_IN, H_DIM);
    hipLaunchKernelGGL(k_wprep, dim3((H_DIM * H_DIM + 255) / 256), dim3(256), 0, stream,
                       cw, cwth, cwtl, H_DIM, H_DIM);
    hipLaunchKernelGGL(k_wprep, dim3((H_DIM * H_DIM + 255) / 256), dim3(256), 0, stream,
                       cw + H_DIM * H_DIM, cwth + H_DIM * H_DIM, cwtl + H_DIM * H_DIM, H_DIM, H_DIM);
    hipLaunchKernelGGL(k_wprep, dim3((H_DIM * D_OUT + 255) / 256), dim3(256), 0, stream,
                       w2, w2th, w2tl, H_DIM, D_OUT);

    int gemmGrid = (N_NODES + 127) / 128;
    // h0 = relu(x @ w1 + b1): f32 + bf16 copies
    hipLaunchKernelGGL((k_mfma_gemm<128, true, true, true, true>), dim3(gemmGrid), dim3(256), 0, stream,
                       x, w1th, w1tl, b1, h0, h0b, N_NODES, D_IN);

    int aggGrid = (int)(((size_t)N_NODES * 64 + 255) / 256);
    // layer 0
    hipLaunchKernelGGL(k_agg, dim3(aggGrid), dim3(256), 0, stream,
                       h0b, h0, offsets, srcA, wgt, dinv, z, N_NODES);
    hipLaunchKernelGGL((k_mfma_gemm<128, false, false, false, true>), dim3(gemmGrid), dim3(256), 0, stream,
                       z, cwth, cwtl, (const float*)nullptr, (float*)nullptr, h1b, N_NODES, H_DIM);
    // layer 1
    hipLaunchKernelGGL(k_agg, dim3(aggGrid), dim3(256), 0, stream,
                       h1b, h0, offsets, srcA, wgt, dinv, z, N_NODES);
    hipLaunchKernelGGL((k_mfma_gemm<128, false, false, true, false>), dim3(gemmGrid), dim3(256), 0, stream,
                       z, cwth + H_DIM * H_DIM, cwtl + H_DIM * H_DIM, (const float*)nullptr, h2,
                       (unsigned short*)nullptr, N_NODES, H_DIM);
    // logits = h2 @ w2 + b2
    hipLaunchKernelGGL((k_mfma_gemm<64, false, true, true, false>), dim3(gemmGrid), dim3(256), 0, stream,
                       h2, w2th, w2tl, b2, logits, (unsigned short*)nullptr, N_NODES, H_DIM);
}